// Round 1
// baseline (317.122 us; speedup 1.0000x reference)
//
#include <hip/hip_runtime.h>

// Problem constants
#define B_SZ 2
#define T_SZ 2048
#define DM   1024
#define NH   16
#define DH   64

typedef __attribute__((ext_vector_type(8))) short bf16x8;
typedef __attribute__((ext_vector_type(4))) float f32x4;
typedef __attribute__((ext_vector_type(4))) unsigned int u32x4;
typedef __attribute__((ext_vector_type(4))) unsigned short u16x4;

__device__ __forceinline__ unsigned short f2bf(float f) {
  unsigned u = __builtin_bit_cast(unsigned, f);
  u += 0x7FFFu + ((u >> 16) & 1u);
  return (unsigned short)(u >> 16);
}
__device__ __forceinline__ unsigned packbf(float lo, float hi) {
  return (unsigned)f2bf(lo) | ((unsigned)f2bf(hi) << 16);
}

// stage 16 f32 -> 16 bf16 into LDS (dst must be 16B aligned, dst+8 too)
__device__ __forceinline__ void stage16(const float* src, unsigned short* dst) {
  const f32x4* ps = (const f32x4*)src;
  f32x4 v0 = ps[0], v1 = ps[1], v2 = ps[2], v3 = ps[3];
  u32x4 w0, w1;
  w0[0] = packbf(v0[0], v0[1]); w0[1] = packbf(v0[2], v0[3]);
  w0[2] = packbf(v1[0], v1[1]); w0[3] = packbf(v1[2], v1[3]);
  w1[0] = packbf(v2[0], v2[1]); w1[1] = packbf(v2[2], v2[3]);
  w1[2] = packbf(v3[0], v3[1]); w1[3] = packbf(v3[2], v3[3]);
  *(u32x4*)dst = w0;
  *(u32x4*)(dst + 8) = w1;
}

// C = A * B^T  (A: MxK row-major, B: NxK row-major), MFMA 16x16x32 bf16.
// AMODE 0: A is f32 (cast on stage). AMODE 1: A is bf16 (Zt, offset by blockIdx.z).
// CMODE 0: write bf16 to QKV head-split layout ws[b][h][t][d].
// CMODE 1: write f32 to out[b][2*m + s][n]  (b,s from blockIdx.z).
template<int AMODE, int CMODE>
__global__ __launch_bounds__(256) void gemm_bt(const void* __restrict__ Aptr, int lda,
                                               const float* __restrict__ Bp, int ldb,
                                               void* __restrict__ Cptr, int K) {
  __shared__ unsigned short lds_a[128][40];
  __shared__ unsigned short lds_b[128][40];
  const int tid  = threadIdx.x;
  const int lane = tid & 63;
  const int wid  = tid >> 6;
  const int wm   = wid >> 1, wn = wid & 1;
  const int l15  = lane & 15, lg = lane >> 4;
  const int mblk = blockIdx.y * 128;
  const int nblk = blockIdx.x * 128;

  const float* Af = (const float*)Aptr;
  const unsigned short* Ab = (const unsigned short*)Aptr;
  long aoff = 0;
  int zb = 0, zs = 0;
  if (CMODE == 1) {
    zb = blockIdx.z >> 1; zs = blockIdx.z & 1;
    aoff = (long)zb * 1024 * 2048 + (long)zs * 1024;
  }

  f32x4 acc[4][4];
#pragma unroll
  for (int i = 0; i < 4; i++)
#pragma unroll
    for (int j = 0; j < 4; j++) acc[i][j] = (f32x4){0.f, 0.f, 0.f, 0.f};

  const int sr = tid >> 1;
  const int sc = (tid & 1) * 16;

  for (int k0 = 0; k0 < K; k0 += 32) {
    if (AMODE == 0) {
      stage16(Af + (long)(mblk + sr) * lda + k0 + sc, &lds_a[sr][sc]);
    } else {
      const u32x4* src = (const u32x4*)(Ab + aoff + (long)(mblk + sr) * lda + k0 + sc);
      *(u32x4*)&lds_a[sr][sc] = src[0];
      *(u32x4*)&lds_a[sr][sc + 8] = src[1];
    }
    stage16(Bp + (long)(nblk + sr) * ldb + k0 + sc, &lds_b[sr][sc]);
    __syncthreads();

    bf16x8 af[4], bf[4];
#pragma unroll
    for (int mi = 0; mi < 4; mi++)
      af[mi] = *(const bf16x8*)&lds_a[wm * 64 + mi * 16 + l15][lg * 8];
#pragma unroll
    for (int nj = 0; nj < 4; nj++)
      bf[nj] = *(const bf16x8*)&lds_b[wn * 64 + nj * 16 + l15][lg * 8];
#pragma unroll
    for (int mi = 0; mi < 4; mi++)
#pragma unroll
      for (int nj = 0; nj < 4; nj++)
        acc[mi][nj] = __builtin_amdgcn_mfma_f32_16x16x32_bf16(af[mi], bf[nj], acc[mi][nj], 0, 0, 0);
    __syncthreads();
  }

#pragma unroll
  for (int mi = 0; mi < 4; mi++) {
#pragma unroll
    for (int nj = 0; nj < 4; nj++) {
#pragma unroll
      for (int r = 0; r < 4; r++) {
        const int i = mblk + wm * 64 + mi * 16 + lg * 4 + r;
        const int n = nblk + wn * 64 + nj * 16 + l15;
        const float v = acc[mi][nj][r];
        if (CMODE == 0) {
          const int b = i >> 11, t = i & 2047, h = n >> 6, d = n & 63;
          ((unsigned short*)Cptr)[((long)(b * NH + h) * T_SZ + t) * DH + d] = f2bf(v);
        } else {
          ((float*)Cptr)[(long)zb * T_SZ * DM + (long)(2 * i + zs) * DM + n] = v;
        }
      }
    }
  }
}

// Flash attention, causal + kv padding mask.
// Qh/Kh/Vh: [b*16+h][t][d] bf16.  Zt out: [b][c=h*64+d][t] bf16 (channel-major).
__global__ __launch_bounds__(256) void attn_kernel(const unsigned short* __restrict__ Qh,
                                                   const unsigned short* __restrict__ Kh,
                                                   const unsigned short* __restrict__ Vh,
                                                   const int* __restrict__ kmask,
                                                   unsigned short* __restrict__ Zt) {
  __shared__ unsigned short lds_k[64][72];
  __shared__ unsigned short lds_vt[64][72];
  __shared__ unsigned short lds_p[4][16][72];
  const int tid = threadIdx.x, lane = tid & 63, w = tid >> 6;
  const int l15 = lane & 15, lg = lane >> 4;
  const int q0 = blockIdx.x * 64;
  const int bh = blockIdx.y;
  const int b = bh >> 4, h = bh & 15;
  const unsigned short* Qb = Qh + ((long)bh << 17);
  const unsigned short* Kb = Kh + ((long)bh << 17);
  const unsigned short* Vb = Vh + ((long)bh << 17);

  const int qrow_a = q0 + w * 16 + l15;          // row for A-fragment of QK^T
  bf16x8 qf0 = *(const bf16x8*)(Qb + ((long)qrow_a << 6) + lg * 8);
  bf16x8 qf1 = *(const bf16x8*)(Qb + ((long)qrow_a << 6) + 32 + lg * 8);

  f32x4 o0 = {0,0,0,0}, o1 = {0,0,0,0}, o2 = {0,0,0,0}, o3 = {0,0,0,0};
  float mrow[4] = {-1e30f, -1e30f, -1e30f, -1e30f};
  float lrow[4] = {0.f, 0.f, 0.f, 0.f};
  const int qc0 = q0 + w * 16 + lg * 4;          // row for C-fragment (+reg)

  const int kr = tid >> 2, kc = (tid & 3) * 16;  // K stage: row, colbase
  const int vr = (tid >> 3) * 2, vc = (tid & 7) * 8;  // V stage: rowpair, dvbase

  for (int j0 = 0; j0 <= q0; j0 += 64) {
    { // stage K tile [64][64]
      const u32x4* src = (const u32x4*)(Kb + ((long)(j0 + kr) << 6) + kc);
      u32x4 a0 = src[0], a1 = src[1];
      *(u32x4*)&lds_k[kr][kc] = a0;
      *(u32x4*)&lds_k[kr][kc + 8] = a1;
    }
    { // stage V transposed: lds_vt[dv][key]
      const u32x4* s0 = (const u32x4*)(Vb + ((long)(j0 + vr) << 6) + vc);
      const u32x4* s1 = (const u32x4*)(Vb + ((long)(j0 + vr + 1) << 6) + vc);
      u32x4 a = s0[0], c = s1[0];
#pragma unroll
      for (int j = 0; j < 8; j++) {
        unsigned lo = (a[j >> 1] >> ((j & 1) * 16)) & 0xFFFFu;
        unsigned hi = (c[j >> 1] >> ((j & 1) * 16)) & 0xFFFFu;
        *(unsigned*)&lds_vt[vc + j][vr] = lo | (hi << 16);
      }
    }
    __syncthreads();

    // S = Q K^T  (per-wave 16 rows x 64 keys)
    f32x4 sa[4];
#pragma unroll
    for (int cb = 0; cb < 4; cb++) {
      bf16x8 kf0 = *(const bf16x8*)&lds_k[cb * 16 + l15][lg * 8];
      bf16x8 kf1 = *(const bf16x8*)&lds_k[cb * 16 + l15][32 + lg * 8];
      f32x4 t = {0.f, 0.f, 0.f, 0.f};
      t = __builtin_amdgcn_mfma_f32_16x16x32_bf16(qf0, kf0, t, 0, 0, 0);
      t = __builtin_amdgcn_mfma_f32_16x16x32_bf16(qf1, kf1, t, 0, 0, 0);
      sa[cb] = t;
    }

    const bool diag = (j0 == q0);
    float pv[4][4];
    float tmax[4] = {-1e30f, -1e30f, -1e30f, -1e30f};
#pragma unroll
    for (int cb = 0; cb < 4; cb++) {
      const int key = j0 + cb * 16 + l15;
      const int mk = kmask[b * T_SZ + key];
#pragma unroll
      for (int r = 0; r < 4; r++) {
        float s = sa[cb][r] * 0.125f;
        const bool ok = (mk != 0) && (!diag || (key <= qc0 + r));
        s = ok ? s : -1e30f;
        pv[cb][r] = s;
        tmax[r] = fmaxf(tmax[r], s);
      }
    }
#pragma unroll
    for (int r = 0; r < 4; r++) {
      float t = tmax[r];
      t = fmaxf(t, __shfl_xor(t, 1, 16));
      t = fmaxf(t, __shfl_xor(t, 2, 16));
      t = fmaxf(t, __shfl_xor(t, 4, 16));
      t = fmaxf(t, __shfl_xor(t, 8, 16));
      const float mnew = fmaxf(mrow[r], t);
      const float sc = __expf(mrow[r] - mnew);
      mrow[r] = mnew;
      float ts = 0.f;
#pragma unroll
      for (int cb = 0; cb < 4; cb++) {
        const float p = __expf(pv[cb][r] - mnew);
        pv[cb][r] = p;
        ts += p;
      }
      ts += __shfl_xor(ts, 1, 16);
      ts += __shfl_xor(ts, 2, 16);
      ts += __shfl_xor(ts, 4, 16);
      ts += __shfl_xor(ts, 8, 16);
      lrow[r] = lrow[r] * sc + ts;
      o0[r] *= sc; o1[r] *= sc; o2[r] *= sc; o3[r] *= sc;
    }

    // P -> wave-private LDS, reread as A-fragment
#pragma unroll
    for (int cb = 0; cb < 4; cb++)
#pragma unroll
      for (int r = 0; r < 4; r++)
        lds_p[w][lg * 4 + r][cb * 16 + l15] = f2bf(pv[cb][r]);
    bf16x8 pf0 = *(const bf16x8*)&lds_p[w][l15][lg * 8];
    bf16x8 pf1 = *(const bf16x8*)&lds_p[w][l15][32 + lg * 8];

#pragma unroll
    for (int nb = 0; nb < 4; nb++) {
      bf16x8 vf0 = *(const bf16x8*)&lds_vt[nb * 16 + l15][lg * 8];
      bf16x8 vf1 = *(const bf16x8*)&lds_vt[nb * 16 + l15][32 + lg * 8];
      f32x4 acc = (nb == 0) ? o0 : (nb == 1) ? o1 : (nb == 2) ? o2 : o3;
      acc = __builtin_amdgcn_mfma_f32_16x16x32_bf16(pf0, vf0, acc, 0, 0, 0);
      acc = __builtin_amdgcn_mfma_f32_16x16x32_bf16(pf1, vf1, acc, 0, 0, 0);
      if (nb == 0) o0 = acc; else if (nb == 1) o1 = acc; else if (nb == 2) o2 = acc; else o3 = acc;
    }
    __syncthreads();
  }

  float inv[4];
#pragma unroll
  for (int r = 0; r < 4; r++) inv[r] = (lrow[r] > 0.f) ? (1.f / lrow[r]) : 0.f;
  const long zbase = (long)(b * DM + h * DH) * T_SZ;
#pragma unroll
  for (int nb = 0; nb < 4; nb++) {
    f32x4 ov = (nb == 0) ? o0 : (nb == 1) ? o1 : (nb == 2) ? o2 : o3;
    u16x4 pk;
#pragma unroll
    for (int r = 0; r < 4; r++) pk[r] = f2bf(ov[r] * inv[r]);
    const int dv = nb * 16 + l15;
    *(u16x4*)&Zt[zbase + (long)dv * T_SZ + qc0] = pk;
  }
}

extern "C" void kernel_launch(void* const* d_in, const int* in_sizes, int n_in,
                              void* d_out, int out_size, void* d_ws, size_t ws_size,
                              hipStream_t stream) {
  const float* q_raw  = (const float*)d_in[0];
  const float* kv_raw = (const float*)d_in[1];
  const int*   kmask  = (const int*)d_in[2];
  const float* Wq = (const float*)d_in[3];
  const float* Wk = (const float*)d_in[4];
  const float* Wv = (const float*)d_in[5];
  const float* Wo = (const float*)d_in[6];
  float* out = (float*)d_out;

  unsigned short* ws = (unsigned short*)d_ws;
  unsigned short* Qh = ws;                     // [32][2048][64] bf16
  unsigned short* Kh = ws + 4194304;
  unsigned short* Vh = ws + 8388608;
  unsigned short* Zt = ws + 12582912;          // [2][1024][2048] bf16

  dim3 gproj(8, 32, 1);
  gemm_bt<0, 0><<<gproj, 256, 0, stream>>>(q_raw, DM, Wq, DM, Qh, DM);
  gemm_bt<0, 0><<<gproj, 256, 0, stream>>>(kv_raw, DM, Wk, DM, Kh, DM);
  gemm_bt<0, 0><<<gproj, 256, 0, stream>>>(kv_raw, DM, Wv, DM, Vh, DM);

  attn_kernel<<<dim3(32, 32), 256, 0, stream>>>(Qh, Kh, Vh, kmask, Zt);

  gemm_bt<1, 1><<<dim3(8, 8, 4), 256, 0, stream>>>(Zt, T_SZ, Wo, DM, out, DM);
}

// Round 2
// 211.392 us; speedup vs baseline: 1.5002x; 1.5002x over previous
//
#include <hip/hip_runtime.h>

// Problem constants
#define B_SZ 2
#define T_SZ 2048
#define DM   1024
#define NH   16
#define DH   64

typedef __attribute__((ext_vector_type(8))) short bf16x8;
typedef __attribute__((ext_vector_type(4))) float f32x4;
typedef __attribute__((ext_vector_type(4))) unsigned int u32x4;
typedef __attribute__((ext_vector_type(4))) unsigned short u16x4;

__device__ __forceinline__ unsigned short f2bf(float f) {
  unsigned u = __builtin_bit_cast(unsigned, f);
  u += 0x7FFFu + ((u >> 16) & 1u);
  return (unsigned short)(u >> 16);
}
__device__ __forceinline__ unsigned packbf(float lo, float hi) {
  return (unsigned)f2bf(lo) | ((unsigned)f2bf(hi) << 16);
}

// stage 16 f32 -> 16 bf16 into LDS, optional scale on the fly
template<bool S>
__device__ __forceinline__ void stage16(const float* src, unsigned short* dst, float scale) {
  const f32x4* ps = (const f32x4*)src;
  f32x4 v0 = ps[0], v1 = ps[1], v2 = ps[2], v3 = ps[3];
  if (S) { v0 *= scale; v1 *= scale; v2 *= scale; v3 *= scale; }
  u32x4 w0, w1;
  w0[0] = packbf(v0[0], v0[1]); w0[1] = packbf(v0[2], v0[3]);
  w0[2] = packbf(v1[0], v1[1]); w0[3] = packbf(v1[2], v1[3]);
  w1[0] = packbf(v2[0], v2[1]); w1[1] = packbf(v2[2], v2[3]);
  w1[2] = packbf(v3[0], v3[1]); w1[3] = packbf(v3[2], v3[3]);
  *(u32x4*)dst = w0;
  *(u32x4*)(dst + 8) = w1;
}

// C = A * B^T (A: MxK row-major, B: NxK row-major), MFMA 16x16x32 bf16.
// AMODE 0: A is f32 (cast on stage). AMODE 1: A is bf16.
// CMODE 0: fused-z pair (z=0: Aptr/Bp/Cptr, z=1: Aptr2/Bp2/Cptr2), write bf16
//          head-split [b][h][t][d]. bscale applies to z=0 B only.
// CMODE 2: A fixed (Wv), B = Bp + z*bZ, write bf16 row-major [z][i*2048+n] (Vt).
// CMODE 1: A bf16 Zt (aoff from z), write f32 out[b][2m+s][n].
template<int AMODE, int CMODE, bool SB>
__global__ __launch_bounds__(256) void gemm_bt(
    const void* __restrict__ Aptr, const void* __restrict__ Aptr2, int lda,
    const float* __restrict__ Bp, const float* __restrict__ Bp2, int ldb, long bZ,
    float bscale, void* __restrict__ Cptr, void* __restrict__ Cptr2, int K) {
  __shared__ unsigned short lds_a[128][40];
  __shared__ unsigned short lds_b[128][40];
  const int tid  = threadIdx.x;
  const int lane = tid & 63;
  const int wid  = tid >> 6;
  const int wm   = wid >> 1, wn = wid & 1;
  const int l15  = lane & 15, lg = lane >> 4;
  const int mblk = blockIdx.y * 128;
  const int nblk = blockIdx.x * 128;
  const int z = blockIdx.z;

  const float* Af = nullptr;
  const unsigned short* Ab = nullptr;
  const float* Bf = Bp;
  void* Cp = Cptr;
  long aoff = 0;
  int zb = 0, zs = 0;
  if constexpr (CMODE == 0) {
    Af = (const float*)(z ? Aptr2 : Aptr);
    Bf = z ? Bp2 : Bp;
    Cp = z ? Cptr2 : Cptr;
  } else if constexpr (CMODE == 2) {
    Af = (const float*)Aptr;
    Bf = Bp + (long)z * bZ;
  } else {
    Ab = (const unsigned short*)Aptr;
    zb = z >> 1; zs = z & 1;
    aoff = (long)zb * 2048 * 1024 + (long)zs * 1024;
  }
  float sB = bscale;
  if constexpr (SB) { if (CMODE == 0 && z) sB = 1.0f; }

  f32x4 acc[4][4];
#pragma unroll
  for (int i = 0; i < 4; i++)
#pragma unroll
    for (int j = 0; j < 4; j++) acc[i][j] = (f32x4){0.f, 0.f, 0.f, 0.f};

  const int sr = tid >> 1;
  const int sc = (tid & 1) * 16;

  for (int k0 = 0; k0 < K; k0 += 32) {
    if (AMODE == 0) {
      stage16<false>(Af + (long)(mblk + sr) * lda + k0 + sc, &lds_a[sr][sc], 1.0f);
    } else {
      const u32x4* src = (const u32x4*)(Ab + aoff + (long)(mblk + sr) * lda + k0 + sc);
      *(u32x4*)&lds_a[sr][sc] = src[0];
      *(u32x4*)&lds_a[sr][sc + 8] = src[1];
    }
    stage16<SB>(Bf + (long)(nblk + sr) * ldb + k0 + sc, &lds_b[sr][sc], sB);
    __syncthreads();

    bf16x8 af[4], bfr[4];
#pragma unroll
    for (int mi = 0; mi < 4; mi++)
      af[mi] = *(const bf16x8*)&lds_a[wm * 64 + mi * 16 + l15][lg * 8];
#pragma unroll
    for (int nj = 0; nj < 4; nj++)
      bfr[nj] = *(const bf16x8*)&lds_b[wn * 64 + nj * 16 + l15][lg * 8];
#pragma unroll
    for (int mi = 0; mi < 4; mi++)
#pragma unroll
      for (int nj = 0; nj < 4; nj++)
        acc[mi][nj] = __builtin_amdgcn_mfma_f32_16x16x32_bf16(af[mi], bfr[nj], acc[mi][nj], 0, 0, 0);
    __syncthreads();
  }

#pragma unroll
  for (int mi = 0; mi < 4; mi++) {
#pragma unroll
    for (int nj = 0; nj < 4; nj++) {
#pragma unroll
      for (int r = 0; r < 4; r++) {
        const int i = mblk + wm * 64 + mi * 16 + lg * 4 + r;
        const int n = nblk + wn * 64 + nj * 16 + l15;
        const float v = acc[mi][nj][r];
        if constexpr (CMODE == 0) {
          const int b = i >> 11, t = i & 2047, h = n >> 6, d = n & 63;
          ((unsigned short*)Cp)[((long)(b * NH + h) * T_SZ + t) * DH + d] = f2bf(v);
        } else if constexpr (CMODE == 2) {
          ((unsigned short*)Cp)[(long)z * 2097152 + (long)i * 2048 + n] = f2bf(v);
        } else {
          ((float*)Cp)[(long)zb * T_SZ * DM + (long)(2 * i + zs) * DM + n] = v;
        }
      }
    }
  }
}

// Flash attention, causal + kv padding mask.
// Qh/Kh: [b*16+h][t][d] bf16 (Q pre-scaled by 1/8). Vt: [b][c=h*64+d][t] bf16.
// Zt out: [b][c][t] bf16 (channel-major).
// Block = pair of q-tiles (p, 31-p): one key sweep updates both segments.
__global__ __launch_bounds__(256) void attn_kernel(const unsigned short* __restrict__ Qh,
                                                   const unsigned short* __restrict__ Kh,
                                                   const unsigned short* __restrict__ Vt,
                                                   const int* __restrict__ kmask,
                                                   unsigned short* __restrict__ Zt) {
  __shared__ unsigned short lds_k[64][72];
  __shared__ unsigned short lds_vt[64][72];
  __shared__ unsigned short lds_p[4][16][72];
  const int tid = threadIdx.x, lane = tid & 63, w = tid >> 6;
  const int l15 = lane & 15, lg = lane >> 4;
  const int p = blockIdx.x;
  const int bh = blockIdx.y, b = bh >> 4, h = bh & 15;
  const int q0a = (31 - p) * 64;   // big segment
  const int q0b = p * 64;          // small segment
  const unsigned short* Qb = Qh + ((long)bh << 17);
  const unsigned short* Kb = Kh + ((long)bh << 17);
  const unsigned short* Vtb = Vt + ((long)(b * DM + h * DH)) * T_SZ;

  const int qra = q0a + w * 16 + l15;
  bf16x8 qa0 = *(const bf16x8*)(Qb + ((long)qra << 6) + lg * 8);
  bf16x8 qa1 = *(const bf16x8*)(Qb + ((long)qra << 6) + 32 + lg * 8);
  const int qrb = q0b + w * 16 + l15;
  bf16x8 qb0 = *(const bf16x8*)(Qb + ((long)qrb << 6) + lg * 8);
  bf16x8 qb1 = *(const bf16x8*)(Qb + ((long)qrb << 6) + 32 + lg * 8);

  f32x4 oa[4], ob[4];
  float ma[4], la[4], mb[4], lb[4];
#pragma unroll
  for (int i = 0; i < 4; i++) {
    oa[i] = (f32x4){0.f, 0.f, 0.f, 0.f}; ob[i] = (f32x4){0.f, 0.f, 0.f, 0.f};
    ma[i] = -1e30f; la[i] = 0.f; mb[i] = -1e30f; lb[i] = 0.f;
  }

  // staging map: 4 lanes cover one 64-elem row (2 x b128 each)
  const int sr = tid >> 2, sc = (tid & 3) * 16;
  const unsigned short* kp = Kb + ((long)sr << 6) + sc;
  const unsigned short* vp = Vtb + (long)sr * T_SZ + sc;
  const int mbase = b * T_SZ + lane;

  u32x4 rk0, rk1, rv0, rv1;
  int rm;
  auto issue = [&](int j0) {
    const u32x4* ks = (const u32x4*)(kp + ((long)j0 << 6));
    rk0 = ks[0]; rk1 = ks[1];
    const u32x4* vs = (const u32x4*)(vp + j0);
    rv0 = vs[0]; rv1 = vs[1];
    rm = kmask[mbase + j0];
  };

  auto segbody = [&](int j0, int q0, const bf16x8& qf0, const bf16x8& qf1,
                     f32x4* o, float* mr, float* lr, unsigned long long kvm) {
    f32x4 sa[4];
#pragma unroll
    for (int cb = 0; cb < 4; cb++) {
      bf16x8 kf0 = *(const bf16x8*)&lds_k[cb * 16 + l15][lg * 8];
      bf16x8 kf1 = *(const bf16x8*)&lds_k[cb * 16 + l15][32 + lg * 8];
      f32x4 t = {0.f, 0.f, 0.f, 0.f};
      t = __builtin_amdgcn_mfma_f32_16x16x32_bf16(qf0, kf0, t, 0, 0, 0);
      t = __builtin_amdgcn_mfma_f32_16x16x32_bf16(qf1, kf1, t, 0, 0, 0);
      sa[cb] = t;
    }
    const bool diag = (j0 == q0);
    const int qc0 = q0 + w * 16 + lg * 4;
    float pv[4][4];
    float tmax[4] = {-1e30f, -1e30f, -1e30f, -1e30f};
#pragma unroll
    for (int cb = 0; cb < 4; cb++) {
      const int kk = cb * 16 + l15;
      const bool mk = (kvm >> kk) & 1ull;
#pragma unroll
      for (int r = 0; r < 4; r++) {
        float s = sa[cb][r];
        const bool ok = mk && (!diag || (j0 + kk <= qc0 + r));
        s = ok ? s : -1e30f;
        pv[cb][r] = s;
        tmax[r] = fmaxf(tmax[r], s);
      }
    }
#pragma unroll
    for (int r = 0; r < 4; r++) {
      float t = tmax[r];
      t = fmaxf(t, __shfl_xor(t, 1, 16));
      t = fmaxf(t, __shfl_xor(t, 2, 16));
      t = fmaxf(t, __shfl_xor(t, 4, 16));
      t = fmaxf(t, __shfl_xor(t, 8, 16));
      const float mnew = fmaxf(mr[r], t);
      const float sc2 = __expf(mr[r] - mnew);
      mr[r] = mnew;
      float ts = 0.f;
#pragma unroll
      for (int cb = 0; cb < 4; cb++) {
        const float pe = __expf(pv[cb][r] - mnew);
        pv[cb][r] = pe;
        ts += pe;
      }
      ts += __shfl_xor(ts, 1, 16);
      ts += __shfl_xor(ts, 2, 16);
      ts += __shfl_xor(ts, 4, 16);
      ts += __shfl_xor(ts, 8, 16);
      lr[r] = lr[r] * sc2 + ts;
      o[0][r] *= sc2; o[1][r] *= sc2; o[2][r] *= sc2; o[3][r] *= sc2;
    }
    // P -> wave-private LDS, reread as A-fragment
#pragma unroll
    for (int cb = 0; cb < 4; cb++)
#pragma unroll
      for (int r = 0; r < 4; r++)
        lds_p[w][lg * 4 + r][cb * 16 + l15] = f2bf(pv[cb][r]);
    bf16x8 pf0 = *(const bf16x8*)&lds_p[w][l15][lg * 8];
    bf16x8 pf1 = *(const bf16x8*)&lds_p[w][l15][32 + lg * 8];
#pragma unroll
    for (int nb = 0; nb < 4; nb++) {
      bf16x8 vf0 = *(const bf16x8*)&lds_vt[nb * 16 + l15][lg * 8];
      bf16x8 vf1 = *(const bf16x8*)&lds_vt[nb * 16 + l15][32 + lg * 8];
      f32x4 t = o[nb];
      t = __builtin_amdgcn_mfma_f32_16x16x32_bf16(pf0, vf0, t, 0, 0, 0);
      t = __builtin_amdgcn_mfma_f32_16x16x32_bf16(pf1, vf1, t, 0, 0, 0);
      o[nb] = t;
    }
  };

  issue(0);
  for (int j0 = 0; j0 <= q0a; j0 += 64) {
    __syncthreads();   // previous tile's LDS reads complete
    *(u32x4*)&lds_k[sr][sc] = rk0;  *(u32x4*)&lds_k[sr][sc + 8] = rk1;
    *(u32x4*)&lds_vt[sr][sc] = rv0; *(u32x4*)&lds_vt[sr][sc + 8] = rv1;
    const unsigned long long kvm = __ballot(rm != 0);
    __syncthreads();   // tile visible
    if (j0 + 64 <= q0a) issue(j0 + 64);   // prefetch overlaps compute
    segbody(j0, q0a, qa0, qa1, oa, ma, la, kvm);
    if (j0 <= q0b) segbody(j0, q0b, qb0, qb1, ob, mb, lb, kvm);
  }

  const long zbase = (long)(b * DM + h * DH) * T_SZ;
  auto epi = [&](f32x4* o, float* lr, int q0) {
    const int qc0 = q0 + w * 16 + lg * 4;
    float inv[4];
#pragma unroll
    for (int r = 0; r < 4; r++) inv[r] = (lr[r] > 0.f) ? (1.f / lr[r]) : 0.f;
#pragma unroll
    for (int nb = 0; nb < 4; nb++) {
      u16x4 pk;
#pragma unroll
      for (int r = 0; r < 4; r++) pk[r] = f2bf(o[nb][r] * inv[r]);
      *(u16x4*)&Zt[zbase + (long)(nb * 16 + l15) * T_SZ + qc0] = pk;
    }
  };
  epi(oa, la, q0a);
  epi(ob, lb, q0b);
}

extern "C" void kernel_launch(void* const* d_in, const int* in_sizes, int n_in,
                              void* d_out, int out_size, void* d_ws, size_t ws_size,
                              hipStream_t stream) {
  const float* q_raw  = (const float*)d_in[0];
  const float* kv_raw = (const float*)d_in[1];
  const int*   kmask  = (const int*)d_in[2];
  const float* Wq = (const float*)d_in[3];
  const float* Wk = (const float*)d_in[4];
  const float* Wv = (const float*)d_in[5];
  const float* Wo = (const float*)d_in[6];
  float* out = (float*)d_out;

  unsigned short* ws = (unsigned short*)d_ws;
  unsigned short* Qh = ws;                     // [32][2048][64] bf16  (q/8)
  unsigned short* Kh = ws + 4194304;           // [32][2048][64] bf16
  unsigned short* Vt = ws + 8388608;           // [2][1024][2048] bf16 (V^T)
  unsigned short* Zt = ws + 12582912;          // [2][1024][2048] bf16

  // Q&K projections fused via grid.z (Q gets 1/sqrt(dh) folded into Wq)
  gemm_bt<0, 0, true><<<dim3(8, 32, 2), 256, 0, stream>>>(
      q_raw, kv_raw, DM, Wq, Wk, DM, 0L, 0.125f, Qh, Kh, DM);
  // V^T projection: Vt[b] = Wv * kv[b]^T
  gemm_bt<0, 2, false><<<dim3(16, 8, 2), 256, 0, stream>>>(
      Wv, nullptr, DM, kv_raw, nullptr, DM, (long)T_SZ * DM, 1.0f, Vt, nullptr, DM);

  attn_kernel<<<dim3(16, 32), 256, 0, stream>>>(Qh, Kh, Vt, kmask, Zt);

  // out[b,2m+s,:] = Zt[b][m][1024s:1024s+1024] @ Wo^T
  gemm_bt<1, 1, false><<<dim3(8, 8, 4), 256, 0, stream>>>(
      Zt, nullptr, T_SZ, Wo, nullptr, DM, 0L, 1.0f, out, nullptr, DM);
}

// Round 4
// 173.334 us; speedup vs baseline: 1.8295x; 1.2196x over previous
//
#include <hip/hip_runtime.h>

#define B_SZ 2
#define T_SZ 2048
#define DM   1024
#define NH   16
#define DH   64

typedef __attribute__((ext_vector_type(8))) short bf16x8;
typedef __attribute__((ext_vector_type(4))) float f32x4;
typedef __attribute__((ext_vector_type(4))) unsigned int u32x4;
typedef __attribute__((ext_vector_type(4))) unsigned short u16x4;

__device__ __forceinline__ unsigned short f2bf(float f) {
  unsigned u = __builtin_bit_cast(unsigned, f);
  u += 0x7FFFu + ((u >> 16) & 1u);
  return (unsigned short)(u >> 16);
}
__device__ __forceinline__ unsigned packbf(float lo, float hi) {
  return (unsigned)f2bf(lo) | ((unsigned)f2bf(hi) << 16);
}

// stage 16 f32 -> 16 bf16 into LDS
__device__ __forceinline__ void stage16(const float* src, unsigned short* dst) {
  const f32x4* ps = (const f32x4*)src;
  f32x4 v0 = ps[0], v1 = ps[1], v2 = ps[2], v3 = ps[3];
  u32x4 w0, w1;
  w0[0] = packbf(v0[0], v0[1]); w0[1] = packbf(v0[2], v0[3]);
  w0[2] = packbf(v1[0], v1[1]); w0[3] = packbf(v1[2], v1[3]);
  w1[0] = packbf(v2[0], v2[1]); w1[1] = packbf(v2[2], v2[3]);
  w1[2] = packbf(v3[0], v3[1]); w1[3] = packbf(v3[2], v3[3]);
  *(u32x4*)dst = w0;
  *(u32x4*)(dst + 8) = w1;
}

// async global->LDS, 16B per lane, lane i lands at base + i*16B
__device__ __forceinline__ void gload16(const unsigned short* g, unsigned short* l) {
  __builtin_amdgcn_global_load_lds(
      (const __attribute__((address_space(1))) unsigned int*)(const void*)g,
      (__attribute__((address_space(3))) unsigned int*)(void*)l, 16, 0, 0);
}

// f32 -> bf16 elementwise convert (16 elems/thread), optional scale
__global__ __launch_bounds__(256) void cvt_kernel(const float* __restrict__ s,
                                                  unsigned short* __restrict__ d,
                                                  int n, float scale) {
  const int i = (blockIdx.x * 256 + threadIdx.x) * 16;
  if (i >= n) return;
  const f32x4* ps = (const f32x4*)(s + i);
  f32x4 v0 = ps[0] * scale, v1 = ps[1] * scale, v2 = ps[2] * scale, v3 = ps[3] * scale;
  u32x4 w0, w1;
  w0[0] = packbf(v0[0], v0[1]); w0[1] = packbf(v0[2], v0[3]);
  w0[2] = packbf(v1[0], v1[1]); w0[3] = packbf(v1[2], v1[3]);
  w1[0] = packbf(v2[0], v2[1]); w1[1] = packbf(v2[2], v2[3]);
  w1[2] = packbf(v3[0], v3[1]); w1[3] = packbf(v3[2], v3[3]);
  *(u32x4*)(d + i) = w0;
  *(u32x4*)(d + i + 8) = w1;
}

// C = A * B^T, tile 128x64, BK=32, MFMA 16x16x32 bf16.
// AMODE: 0 = A f32 (stage16), 1 = A bf16 (global_load_lds)
// BMODE: 0 = B f32 (stage16), 1 = B bf16 (global_load_lds)
// CMODE 0: z selects (A0,B0,C0)/(A1,B1,C1); write bf16 head-split [b][h][t][d]
// CMODE 2: A fixed; B = B0 + z*bZ; write bf16 row-major [z][i*2048+n]   (Vt)
// CMODE 1: A bf16 + aoff(z); write f32 out[zb][2i+zs][n]
template<int AMODE, int BMODE, int CMODE>
__global__ __launch_bounds__(256) void gemm2(
    const void* __restrict__ A0, const void* __restrict__ A1, int lda,
    const void* __restrict__ B0, const void* __restrict__ B1, int ldb, long bZ,
    void* __restrict__ C0, void* __restrict__ C1, int K) {
  __shared__ unsigned short As[128 * 32];
  __shared__ unsigned short Bs[64 * 32];
  const int tid = threadIdx.x, lane = tid & 63, w = tid >> 6;
  const int wm = w >> 1, wn = w & 1;
  const int l15 = lane & 15, lg = lane >> 4;
  const int mblk = blockIdx.y * 128, nblk = blockIdx.x * 64;
  const int z = blockIdx.z;

  const void* Ap; const void* Bp; void* Cp;
  long aoff = 0; int zb = 0, zs = 0;
  if constexpr (CMODE == 0) {
    Ap = z ? A1 : A0; Bp = z ? B1 : B0; Cp = z ? C1 : C0;
  } else if constexpr (CMODE == 2) {
    Ap = A0; Cp = C0;
    if constexpr (BMODE == 1) Bp = (const void*)((const unsigned short*)B0 + (long)z * bZ);
    else                      Bp = (const void*)((const float*)B0 + (long)z * bZ);
  } else {
    Ap = A0; Bp = B0; Cp = C0;
    zb = z >> 1; zs = z & 1;
    aoff = (long)zb * 2097152 + (long)zs * 1024;
  }

  f32x4 acc[4][2];
#pragma unroll
  for (int i = 0; i < 4; i++)
#pragma unroll
    for (int j = 0; j < 2; j++) acc[i][j] = (f32x4){0.f, 0.f, 0.f, 0.f};

  const int asr = tid >> 1, asc = (tid & 1) * 16;              // f32 stage map
  const int agr = w * 32 + (lane >> 2), agc = (lane & 3) * 8;  // A gload map
  const int bgr = w * 16 + (lane >> 2), bgc = (lane & 3) * 8;  // B gload map

  for (int k0 = 0; k0 < K; k0 += 32) {
    if constexpr (AMODE == 0) {
      stage16((const float*)Ap + (long)(mblk + asr) * lda + k0 + asc, &As[asr * 32 + asc]);
    } else {
      const unsigned short* Ab = (const unsigned short*)Ap + aoff;
      gload16(Ab + (long)(mblk + agr) * lda + k0 + agc, &As[w * 1024]);
      gload16(Ab + (long)(mblk + agr + 16) * lda + k0 + agc, &As[w * 1024 + 512]);
    }
    if constexpr (BMODE == 0) {
      if (tid < 128)
        stage16((const float*)Bp + (long)(nblk + asr) * ldb + k0 + asc, &Bs[asr * 32 + asc]);
    } else {
      gload16((const unsigned short*)Bp + (long)(nblk + bgr) * ldb + k0 + bgc, &Bs[w * 512]);
    }
    __syncthreads();

    bf16x8 af[4], bfr[2];
#pragma unroll
    for (int mi = 0; mi < 4; mi++)
      af[mi] = *(const bf16x8*)&As[(wm * 64 + mi * 16 + l15) * 32 + lg * 8];
#pragma unroll
    for (int nj = 0; nj < 2; nj++)
      bfr[nj] = *(const bf16x8*)&Bs[(wn * 32 + nj * 16 + l15) * 32 + lg * 8];
#pragma unroll
    for (int mi = 0; mi < 4; mi++)
#pragma unroll
      for (int nj = 0; nj < 2; nj++)
        acc[mi][nj] = __builtin_amdgcn_mfma_f32_16x16x32_bf16(af[mi], bfr[nj], acc[mi][nj], 0, 0, 0);
    __syncthreads();
  }

#pragma unroll
  for (int mi = 0; mi < 4; mi++) {
#pragma unroll
    for (int nj = 0; nj < 2; nj++) {
#pragma unroll
      for (int r = 0; r < 4; r++) {
        const int i = mblk + wm * 64 + mi * 16 + lg * 4 + r;
        const int n = nblk + wn * 32 + nj * 16 + l15;
        const float v = acc[mi][nj][r];
        if constexpr (CMODE == 0) {
          const int b = i >> 11, t = i & 2047, h = n >> 6, d = n & 63;
          ((unsigned short*)Cp)[((long)(b * NH + h) * T_SZ + t) * DH + d] = f2bf(v);
        } else if constexpr (CMODE == 2) {
          ((unsigned short*)Cp)[(long)z * 2097152 + (long)i * 2048 + n] = f2bf(v);
        } else {
          ((float*)Cp)[(long)zb * T_SZ * DM + (long)(2 * i + zs) * DM + n] = v;
        }
      }
    }
  }
}

// Flash attention, causal + kv padding mask. Dual-segment ILP version.
// Qh/Kh: [b*16+h][t][d] bf16 (Q pre-scaled 1/8). Vt/Zt: [b][c][t] bf16.
__global__ __launch_bounds__(256) void attn_kernel(const unsigned short* __restrict__ Qh,
                                                   const unsigned short* __restrict__ Kh,
                                                   const unsigned short* __restrict__ Vt,
                                                   const int* __restrict__ kmask,
                                                   unsigned short* __restrict__ Zt) {
  __shared__ unsigned short lds_k[64][72];
  __shared__ unsigned short lds_vt[64][72];
  __shared__ unsigned short lds_pa[4][16][72];
  __shared__ unsigned short lds_pb[4][16][72];
  const int tid = threadIdx.x, lane = tid & 63, w = tid >> 6;
  const int l15 = lane & 15, lg = lane >> 4;
  // XCD-aware decode: all 16 p-blocks of a bh land on one XCD (K/V L2-resident)
  const int wg = blockIdx.x;
  const int xcd = wg & 7, lin = wg >> 3;
  const int bh = xcd * 4 + (lin >> 4);
  const int p = lin & 15;
  const int b = bh >> 4;
  const int h = bh & 15;
  const int q0a = (31 - p) * 64;
  const int q0b = p * 64;
  const unsigned short* Qb = Qh + ((long)bh << 17);
  const unsigned short* Kb = Kh + ((long)bh << 17);
  const unsigned short* Vtb = Vt + ((long)(b * DM + h * DH)) * T_SZ;

  const int qra = q0a + w * 16 + l15;
  bf16x8 qa0 = *(const bf16x8*)(Qb + ((long)qra << 6) + lg * 8);
  bf16x8 qa1 = *(const bf16x8*)(Qb + ((long)qra << 6) + 32 + lg * 8);
  const int qrb = q0b + w * 16 + l15;
  bf16x8 qb0 = *(const bf16x8*)(Qb + ((long)qrb << 6) + lg * 8);
  bf16x8 qb1 = *(const bf16x8*)(Qb + ((long)qrb << 6) + 32 + lg * 8);

  f32x4 oa[4], ob[4];
  float ma[4], la[4], mb[4], lb[4];
#pragma unroll
  for (int i = 0; i < 4; i++) {
    oa[i] = (f32x4){0.f, 0.f, 0.f, 0.f}; ob[i] = (f32x4){0.f, 0.f, 0.f, 0.f};
    ma[i] = -1e30f; la[i] = 0.f; mb[i] = -1e30f; lb[i] = 0.f;
  }

  const int sr = tid >> 2, sc = (tid & 3) * 16;
  const unsigned short* kp = Kb + ((long)sr << 6) + sc;
  const unsigned short* vp = Vtb + (long)sr * T_SZ + sc;
  const int mbase = b * T_SZ + lane;

  u32x4 rk0, rk1, rv0, rv1;
  int rm;
  auto issue = [&](int j0) {
    const u32x4* ks = (const u32x4*)(kp + ((long)j0 << 6));
    rk0 = ks[0]; rk1 = ks[1];
    const u32x4* vs = (const u32x4*)(vp + j0);
    rv0 = vs[0]; rv1 = vs[1];
    rm = kmask[mbase + j0];
  };

  const int qc0a = q0a + w * 16 + lg * 4;
  const int qc0b = q0b + w * 16 + lg * 4;

  auto body = [&](int j0, bool dob, unsigned long long kvm) {
    f32x4 sa[4], sb[4];
    __builtin_amdgcn_s_setprio(1);
#pragma unroll
    for (int cb = 0; cb < 4; cb++) {
      bf16x8 kf0 = *(const bf16x8*)&lds_k[cb * 16 + l15][lg * 8];
      bf16x8 kf1 = *(const bf16x8*)&lds_k[cb * 16 + l15][32 + lg * 8];
      f32x4 t = {0.f, 0.f, 0.f, 0.f};
      t = __builtin_amdgcn_mfma_f32_16x16x32_bf16(qa0, kf0, t, 0, 0, 0);
      t = __builtin_amdgcn_mfma_f32_16x16x32_bf16(qa1, kf1, t, 0, 0, 0);
      sa[cb] = t;
      if (dob) {
        f32x4 u = {0.f, 0.f, 0.f, 0.f};
        u = __builtin_amdgcn_mfma_f32_16x16x32_bf16(qb0, kf0, u, 0, 0, 0);
        u = __builtin_amdgcn_mfma_f32_16x16x32_bf16(qb1, kf1, u, 0, 0, 0);
        sb[cb] = u;
      }
    }
    __builtin_amdgcn_s_setprio(0);

    const bool dga = (j0 == q0a), dgb = (j0 == q0b);
    float pa[4][4], pb[4][4];
    float tma[4] = {-1e30f, -1e30f, -1e30f, -1e30f};
    float tmb[4] = {-1e30f, -1e30f, -1e30f, -1e30f};
#pragma unroll
    for (int cb = 0; cb < 4; cb++) {
      const int kk = cb * 16 + l15;
      const bool mk = (kvm >> kk) & 1ull;
#pragma unroll
      for (int r = 0; r < 4; r++) {
        float s = sa[cb][r];
        bool ok = mk && (!dga || (j0 + kk <= qc0a + r));
        s = ok ? s : -1e30f;
        pa[cb][r] = s;
        tma[r] = fmaxf(tma[r], s);
        if (dob) {
          float s2 = sb[cb][r];
          bool ok2 = mk && (!dgb || (j0 + kk <= qc0b + r));
          s2 = ok2 ? s2 : -1e30f;
          pb[cb][r] = s2;
          tmb[r] = fmaxf(tmb[r], s2);
        }
      }
    }
#pragma unroll
    for (int r = 0; r < 4; r++) {
      float t = tma[r];
      t = fmaxf(t, __shfl_xor(t, 1, 16));
      t = fmaxf(t, __shfl_xor(t, 2, 16));
      t = fmaxf(t, __shfl_xor(t, 4, 16));
      t = fmaxf(t, __shfl_xor(t, 8, 16));
      const float mnew = fmaxf(ma[r], t);
      const float sc2 = __expf(ma[r] - mnew);
      ma[r] = mnew;
      float ts = 0.f;
#pragma unroll
      for (int cb = 0; cb < 4; cb++) {
        const float pe = __expf(pa[cb][r] - mnew);
        pa[cb][r] = pe;
        ts += pe;
      }
      ts += __shfl_xor(ts, 1, 16);
      ts += __shfl_xor(ts, 2, 16);
      ts += __shfl_xor(ts, 4, 16);
      ts += __shfl_xor(ts, 8, 16);
      la[r] = la[r] * sc2 + ts;
      oa[0][r] *= sc2; oa[1][r] *= sc2; oa[2][r] *= sc2; oa[3][r] *= sc2;
      if (dob) {
        float t2 = tmb[r];
        t2 = fmaxf(t2, __shfl_xor(t2, 1, 16));
        t2 = fmaxf(t2, __shfl_xor(t2, 2, 16));
        t2 = fmaxf(t2, __shfl_xor(t2, 4, 16));
        t2 = fmaxf(t2, __shfl_xor(t2, 8, 16));
        const float mnew2 = fmaxf(mb[r], t2);
        const float sc3 = __expf(mb[r] - mnew2);
        mb[r] = mnew2;
        float ts2 = 0.f;
#pragma unroll
        for (int cb = 0; cb < 4; cb++) {
          const float pe = __expf(pb[cb][r] - mnew2);
          pb[cb][r] = pe;
          ts2 += pe;
        }
        ts2 += __shfl_xor(ts2, 1, 16);
        ts2 += __shfl_xor(ts2, 2, 16);
        ts2 += __shfl_xor(ts2, 4, 16);
        ts2 += __shfl_xor(ts2, 8, 16);
        lb[r] = lb[r] * sc3 + ts2;
        ob[0][r] *= sc3; ob[1][r] *= sc3; ob[2][r] *= sc3; ob[3][r] *= sc3;
      }
    }

#pragma unroll
    for (int cb = 0; cb < 4; cb++)
#pragma unroll
      for (int r = 0; r < 4; r++) {
        lds_pa[w][lg * 4 + r][cb * 16 + l15] = f2bf(pa[cb][r]);
        if (dob) lds_pb[w][lg * 4 + r][cb * 16 + l15] = f2bf(pb[cb][r]);
      }
    bf16x8 pfa0 = *(const bf16x8*)&lds_pa[w][l15][lg * 8];
    bf16x8 pfa1 = *(const bf16x8*)&lds_pa[w][l15][32 + lg * 8];
    bf16x8 pfb0, pfb1;
    if (dob) {
      pfb0 = *(const bf16x8*)&lds_pb[w][l15][lg * 8];
      pfb1 = *(const bf16x8*)&lds_pb[w][l15][32 + lg * 8];
    }
    __builtin_amdgcn_s_setprio(1);
#pragma unroll
    for (int nb = 0; nb < 4; nb++) {
      bf16x8 vf0 = *(const bf16x8*)&lds_vt[nb * 16 + l15][lg * 8];
      bf16x8 vf1 = *(const bf16x8*)&lds_vt[nb * 16 + l15][32 + lg * 8];
      f32x4 t = oa[nb];
      t = __builtin_amdgcn_mfma_f32_16x16x32_bf16(pfa0, vf0, t, 0, 0, 0);
      t = __builtin_amdgcn_mfma_f32_16x16x32_bf16(pfa1, vf1, t, 0, 0, 0);
      oa[nb] = t;
      if (dob) {
        f32x4 u = ob[nb];
        u = __builtin_amdgcn_mfma_f32_16x16x32_bf16(pfb0, vf0, u, 0, 0, 0);
        u = __builtin_amdgcn_mfma_f32_16x16x32_bf16(pfb1, vf1, u, 0, 0, 0);
        ob[nb] = u;
      }
    }
    __builtin_amdgcn_s_setprio(0);
  };

  issue(0);
  int j0 = 0;
  for (; j0 <= q0b; j0 += 64) {
    __syncthreads();
    *(u32x4*)&lds_k[sr][sc] = rk0;  *(u32x4*)&lds_k[sr][sc + 8] = rk1;
    *(u32x4*)&lds_vt[sr][sc] = rv0; *(u32x4*)&lds_vt[sr][sc + 8] = rv1;
    const unsigned long long kvm = __ballot(rm != 0);
    __syncthreads();
    if (j0 + 64 <= q0a) issue(j0 + 64);
    body(j0, true, kvm);
  }
  for (; j0 <= q0a; j0 += 64) {
    __syncthreads();
    *(u32x4*)&lds_k[sr][sc] = rk0;  *(u32x4*)&lds_k[sr][sc + 8] = rk1;
    *(u32x4*)&lds_vt[sr][sc] = rv0; *(u32x4*)&lds_vt[sr][sc + 8] = rv1;
    const unsigned long long kvm = __ballot(rm != 0);
    __syncthreads();
    if (j0 + 64 <= q0a) issue(j0 + 64);
    body(j0, false, kvm);
  }

  const long zbase = (long)(b * DM + h * DH) * T_SZ;
  auto epi = [&](f32x4* o, float* lr, int qc0) {
    float inv[4];
#pragma unroll
    for (int r = 0; r < 4; r++) inv[r] = (lr[r] > 0.f) ? (1.f / lr[r]) : 0.f;
#pragma unroll
    for (int nb = 0; nb < 4; nb++) {
      u16x4 pk;
#pragma unroll
      for (int r = 0; r < 4; r++) pk[r] = f2bf(o[nb][r] * inv[r]);
      *(u16x4*)&Zt[zbase + (long)(nb * 16 + l15) * T_SZ + qc0] = pk;
    }
  };
  epi(oa, la, qc0a);
  epi(ob, lb, qc0b);
}

extern "C" void kernel_launch(void* const* d_in, const int* in_sizes, int n_in,
                              void* d_out, int out_size, void* d_ws, size_t ws_size,
                              hipStream_t stream) {
  const float* q_raw  = (const float*)d_in[0];
  const float* kv_raw = (const float*)d_in[1];
  const int*   kmask  = (const int*)d_in[2];
  const float* Wq = (const float*)d_in[3];
  const float* Wk = (const float*)d_in[4];
  const float* Wv = (const float*)d_in[5];
  const float* Wo = (const float*)d_in[6];
  float* out = (float*)d_out;

  unsigned short* ws = (unsigned short*)d_ws;
  unsigned short* Qh = ws;                     // [32][2048][64] bf16 (q/8)  8 MB
  unsigned short* Kh = ws + 4194304;           //                            8 MB
  unsigned short* Vt = ws + 8388608;           // [2][1024][2048] bf16       8 MB
  unsigned short* Zt = ws + 12582912;          // [2][1024][2048] bf16       8 MB
  // full path (needs 58.7 MB of ws): everything bf16
  const bool full = ws_size >= (size_t)58720256;

  if (full) {
    unsigned short* wqb = ws + 16777216;
    unsigned short* wkb = ws + 17825792;
    unsigned short* wvb = ws + 18874368;
    unsigned short* wob = ws + 19922944;
    unsigned short* qb  = ws + 20971520;
    unsigned short* kvb = ws + 25165824;
    cvt_kernel<<<256, 256, 0, stream>>>(Wq, wqb, 1048576, 0.125f);
    cvt_kernel<<<256, 256, 0, stream>>>(Wk, wkb, 1048576, 1.0f);
    cvt_kernel<<<256, 256, 0, stream>>>(Wv, wvb, 1048576, 1.0f);
    cvt_kernel<<<256, 256, 0, stream>>>(Wo, wob, 1048576, 1.0f);
    cvt_kernel<<<1024, 256, 0, stream>>>(q_raw, qb, 4194304, 1.0f);
    cvt_kernel<<<1024, 256, 0, stream>>>(kv_raw, kvb, 4194304, 1.0f);
    gemm2<1, 1, 0><<<dim3(16, 32, 2), 256, 0, stream>>>(
        qb, kvb, DM, wqb, wkb, DM, 0L, Qh, Kh, DM);
    gemm2<1, 1, 2><<<dim3(32, 8, 2), 256, 0, stream>>>(
        wvb, nullptr, DM, kvb, nullptr, DM, 2097152L, Vt, nullptr, DM);
    attn_kernel<<<dim3(512), 256, 0, stream>>>(Qh, Kh, Vt, kmask, Zt);
    gemm2<1, 1, 1><<<dim3(16, 8, 4), 256, 0, stream>>>(
        Zt, nullptr, T_SZ, wob, nullptr, DM, 0L, out, nullptr, DM);   // K=DM (fixed)
  } else {
    // conservative path: fits in proven 33.5 MB. Weight bf16 buffers alias the
    // Zt region (dead before attn overwrites Zt); Wo stays f32-staged.
    unsigned short* wqb = ws + 12582912;
    unsigned short* wkb = ws + 13631488;
    unsigned short* wvb = ws + 14680064;
    cvt_kernel<<<256, 256, 0, stream>>>(Wq, wqb, 1048576, 0.125f);
    cvt_kernel<<<256, 256, 0, stream>>>(Wk, wkb, 1048576, 1.0f);
    cvt_kernel<<<256, 256, 0, stream>>>(Wv, wvb, 1048576, 1.0f);
    gemm2<0, 1, 0><<<dim3(16, 32, 2), 256, 0, stream>>>(
        q_raw, kv_raw, DM, wqb, wkb, DM, 0L, Qh, Kh, DM);
    gemm2<1, 0, 2><<<dim3(32, 8, 2), 256, 0, stream>>>(
        wvb, nullptr, DM, kv_raw, nullptr, DM, 2097152L, Vt, nullptr, DM);
    attn_kernel<<<dim3(512), 256, 0, stream>>>(Qh, Kh, Vt, kmask, Zt);
    gemm2<1, 0, 1><<<dim3(16, 8, 4), 256, 0, stream>>>(
        Zt, nullptr, T_SZ, Wo, nullptr, DM, 0L, out, nullptr, DM);    // K=DM (fixed)
  }
}